// Round 4
// baseline (505.028 us; speedup 1.0000x reference)
//
#include <hip/hip_runtime.h>

#define DD 128
#define GG 256

// ---------------- multi-copy degree histograms ----------------
// copy index = blockIdx.x % NC; 4 edges per thread (int4 loads).
__global__ __launch_bounds__(256) void k_hist(const int* __restrict__ src, const int* __restrict__ dst,
                                              int* __restrict__ hist_out, int* __restrict__ hist_in,
                                              int E, int N, int NC) {
    int c = blockIdx.x % NC;
    int* ho = hist_out + (size_t)c * N;
    int* hi = hist_in + (size_t)c * N;
    int e = (blockIdx.x * 256 + threadIdx.x) * 4;
    if (e + 3 < E) {
        int4 s4 = *(const int4*)&src[e];
        int4 d4 = *(const int4*)&dst[e];
        atomicAdd(&ho[s4.x], 1); atomicAdd(&hi[d4.x], 1);
        atomicAdd(&ho[s4.y], 1); atomicAdd(&hi[d4.y], 1);
        atomicAdd(&ho[s4.z], 1); atomicAdd(&hi[d4.z], 1);
        atomicAdd(&ho[s4.w], 1); atomicAdd(&hi[d4.w], 1);
    } else {
        for (int j = 0; j < 4 && e + j < E; ++j) {
            atomicAdd(&ho[src[e + j]], 1);
            atomicAdd(&hi[dst[e + j]], 1);
        }
    }
}

// reduce copies -> deg_in (for scan), norms
__global__ void k_reduce(const int* __restrict__ hist_out, const int* __restrict__ hist_in,
                         float* __restrict__ norm_out, float* __restrict__ norm_in,
                         int* __restrict__ deg_in, int N, int NC) {
    int n = blockIdx.x * blockDim.x + threadIdx.x;
    if (n >= N) return;
    int so = 0, si = 0;
    for (int c = 0; c < NC; ++c) {
        so += hist_out[(size_t)c * N + n];
        si += hist_in[(size_t)c * N + n];
    }
    norm_out[n] = rsqrtf(fmaxf((float)so, 1.0f));
    norm_in[n] = rsqrtf(fmaxf((float)si, 1.0f));
    deg_in[n] = si;
}

// per-(copy,node) fill base: base[c][n] = row_ptr[n] + sum_{c'<c} hist_in[c'][n]
__global__ void k_base(const int* __restrict__ hist_in, const int* __restrict__ row_ptr,
                       int* __restrict__ base, int N, int NC) {
    int n = blockIdx.x * blockDim.x + threadIdx.x;
    if (n >= N) return;
    int run = row_ptr[n];
    for (int c = 0; c < NC; ++c) {
        int h = hist_in[(size_t)c * N + n];
        base[(size_t)c * N + n] = run;
        run += h;
    }
}

// g_start[g] = lower_bound(gid, g), g in [0, G]; gid sorted.
__global__ void k_gstart(const int* __restrict__ gid, int* g_start, int N, int G) {
    int g = blockIdx.x * blockDim.x + threadIdx.x;
    if (g > G) return;
    int lo = 0, hi = N;
    while (lo < hi) {
        int mid = (lo + hi) >> 1;
        if (gid[mid] < g) lo = mid + 1; else hi = mid;
    }
    g_start[g] = lo;
}

// ---------------- 3-phase scan: deg_in -> row_ptr ----------------
__global__ __launch_bounds__(256) void k_scan_a(const int* __restrict__ deg, int* bsum, int n) {
    __shared__ int wsum[4];
    int base = blockIdx.x * 1024 + threadIdx.x * 4;
    int s = 0;
    #pragma unroll
    for (int j = 0; j < 4; ++j) s += (base + j < n) ? deg[base + j] : 0;
    #pragma unroll
    for (int off = 32; off; off >>= 1) s += __shfl_xor(s, off);
    int lane = threadIdx.x & 63, w = threadIdx.x >> 6;
    if (lane == 0) wsum[w] = s;
    __syncthreads();
    if (threadIdx.x == 0) bsum[blockIdx.x] = wsum[0] + wsum[1] + wsum[2] + wsum[3];
}

__global__ void k_scan_b(int* bsum, int nblk, int* row_ptr, int n) {
    int lane = threadIdx.x;  // 64 threads
    int carry = 0;
    for (int base = 0; base < nblk; base += 64) {
        int i = base + lane;
        int v = (i < nblk) ? bsum[i] : 0;
        int s = v;
        #pragma unroll
        for (int off = 1; off < 64; off <<= 1) {
            int u = __shfl_up(s, off);
            if (lane >= off) s += u;
        }
        if (i < nblk) bsum[i] = carry + s - v;  // exclusive
        carry += __shfl(s, 63);
    }
    if (lane == 0) row_ptr[n] = carry;
}

__global__ __launch_bounds__(256) void k_scan_c(const int* __restrict__ deg, const int* __restrict__ bsum,
                                                int* row_ptr, int n) {
    __shared__ int wsum[4];
    int t = threadIdx.x;
    int base = blockIdx.x * 1024 + t * 4;
    int v[4];
    #pragma unroll
    for (int j = 0; j < 4; ++j) v[j] = (base + j < n) ? deg[base + j] : 0;
    int ts = v[0] + v[1] + v[2] + v[3];
    int lane = t & 63, w = t >> 6;
    int incl = ts;
    #pragma unroll
    for (int off = 1; off < 64; off <<= 1) {
        int u = __shfl_up(incl, off);
        if (lane >= off) incl += u;
    }
    if (lane == 63) wsum[w] = incl;
    __syncthreads();
    int woff = 0;
    for (int j = 0; j < w; ++j) woff += wsum[j];
    int run = bsum[blockIdx.x] + woff + incl - ts;
    #pragma unroll
    for (int j = 0; j < 4; ++j) {
        if (base + j < n) row_ptr[base + j] = run;
        run += v[j];
    }
}

// fill CSR via per-copy base counters; same block->copy mapping as k_hist.
__global__ __launch_bounds__(256) void k_fill(const int* __restrict__ src, const int* __restrict__ dst,
                                              int* __restrict__ base, int* __restrict__ col_src,
                                              int E, int N, int NC) {
    int c = blockIdx.x % NC;
    int* bc = base + (size_t)c * N;
    int e = (blockIdx.x * 256 + threadIdx.x) * 4;
    if (e + 3 < E) {
        int4 s4 = *(const int4*)&src[e];
        int4 d4 = *(const int4*)&dst[e];
        int p0 = atomicAdd(&bc[d4.x], 1);
        int p1 = atomicAdd(&bc[d4.y], 1);
        int p2 = atomicAdd(&bc[d4.z], 1);
        int p3 = atomicAdd(&bc[d4.w], 1);
        col_src[p0] = s4.x;
        col_src[p1] = s4.y;
        col_src[p2] = s4.z;
        col_src[p3] = s4.w;
    } else {
        for (int j = 0; j < 4 && e + j < E; ++j) {
            int pos = atomicAdd(&bc[dst[e + j]], 1);
            col_src[pos] = src[e + j];
        }
    }
}

// pre-scale rows: hn[n] = h[n] * norm_out[n]  (float4 per thread)
__global__ void k_scale(const float* __restrict__ h, const float* __restrict__ norm_out,
                        float* __restrict__ hn, int N) {
    int i = blockIdx.x * blockDim.x + threadIdx.x;  // over N*32 float4s
    if (i < N * 32) {
        int n = i >> 5;
        float4 v = ((const float4*)h)[i];
        float s = norm_out[n];
        v.x *= s; v.y *= s; v.z *= s; v.w *= s;
        ((float4*)hn)[i] = v;
    }
}

// pull-mode aggregation: input rows pre-scaled by norm_out.
// 32 threads/node (float4 each), 8 nodes per 256-thread block, unroll x4.
__global__ __launch_bounds__(256) void k_agg(const float* __restrict__ hn, const float* __restrict__ norm_in,
                                             const int* __restrict__ row_ptr, const int* __restrict__ col_src,
                                             float* __restrict__ agg, int N) {
    int t = threadIdx.x;
    int tc = t & 31;          // col quad
    int n = blockIdx.x * 8 + (t >> 5);
    if (n >= N) return;
    int beg = row_ptr[n], end = row_ptr[n + 1];
    float4 acc = make_float4(0.f, 0.f, 0.f, 0.f);
    int k = beg;
    for (; k + 3 < end; k += 4) {
        int s0 = col_src[k];
        int s1 = col_src[k + 1];
        int s2 = col_src[k + 2];
        int s3 = col_src[k + 3];
        float4 v0 = *(const float4*)&hn[(size_t)s0 * DD + tc * 4];
        float4 v1 = *(const float4*)&hn[(size_t)s1 * DD + tc * 4];
        float4 v2 = *(const float4*)&hn[(size_t)s2 * DD + tc * 4];
        float4 v3 = *(const float4*)&hn[(size_t)s3 * DD + tc * 4];
        acc.x += v0.x + v1.x + v2.x + v3.x;
        acc.y += v0.y + v1.y + v2.y + v3.y;
        acc.z += v0.z + v1.z + v2.z + v3.z;
        acc.w += v0.w + v1.w + v2.w + v3.w;
    }
    for (; k < end; ++k) {
        int s = col_src[k];
        float4 v = *(const float4*)&hn[(size_t)s * DD + tc * 4];
        acc.x += v.x; acc.y += v.y; acc.z += v.z; acc.w += v.w;
    }
    float ni = norm_in[n];
    acc.x *= ni; acc.y *= ni; acc.z *= ni; acc.w *= ni;
    *(float4*)&agg[(size_t)n * DD + tc * 4] = acc;
}

// GEMM: out[n] = relu(A[n] @ W + b) [* scale[n] if scale], A:[N,128], W:[128,128]
__global__ __launch_bounds__(256) void k_mm(const float* __restrict__ A, const float* __restrict__ Wl,
                                            const float* __restrict__ bl, const float* __restrict__ scale,
                                            float* __restrict__ out, int N) {
    __shared__ float Wlds[32 * 128];  // 16 KB
    __shared__ float Alds[64 * 32];   // 8 KB
    int tid = threadIdx.x;
    int tj = tid & 31;
    int tn = tid >> 5;
    int n0 = blockIdx.x * 64;
    float acc[8][4] = {};

    for (int kk = 0; kk < 128; kk += 32) {
        __syncthreads();
        for (int q = tid; q < 1024; q += 256) {
            int r = q >> 5;
            int c = (q & 31) * 4;
            *(float4*)&Wlds[r * 128 + c] = *(const float4*)&Wl[(size_t)(kk + r) * 128 + c];
        }
        for (int q = tid; q < 512; q += 256) {
            int r = q >> 3;
            int c = (q & 7) * 4;
            int n = n0 + r;
            float4 v = make_float4(0.f, 0.f, 0.f, 0.f);
            if (n < N) v = *(const float4*)&A[(size_t)n * 128 + kk + c];
            *(float4*)&Alds[r * 32 + c] = v;
        }
        __syncthreads();
        #pragma unroll 4
        for (int kl = 0; kl < 32; ++kl) {
            float4 w = *(float4*)&Wlds[kl * 128 + tj * 4];
            #pragma unroll
            for (int i = 0; i < 8; ++i) {
                float a = Alds[(tn * 8 + i) * 32 + kl];
                acc[i][0] += a * w.x;
                acc[i][1] += a * w.y;
                acc[i][2] += a * w.z;
                acc[i][3] += a * w.w;
            }
        }
    }
    float4 bv = *(const float4*)&bl[tj * 4];
    #pragma unroll
    for (int i = 0; i < 8; ++i) {
        int n = n0 + tn * 8 + i;
        if (n < N) {
            float sc = scale ? scale[n] : 1.0f;
            float4 o;
            o.x = fmaxf(acc[i][0] + bv.x, 0.f) * sc;
            o.y = fmaxf(acc[i][1] + bv.y, 0.f) * sc;
            o.z = fmaxf(acc[i][2] + bv.z, 0.f) * sc;
            o.w = fmaxf(acc[i][3] + bv.w, 0.f) * sc;
            *(float4*)&out[(size_t)n * 128 + tj * 4] = o;
        }
    }
}

// pooled mean readout: one block per graph, contiguous row range, no atomics.
__global__ __launch_bounds__(128) void k_pool(const float* __restrict__ h, const int* __restrict__ g_start,
                                              float* __restrict__ out) {
    int g = blockIdx.x;
    int t = threadIdx.x;  // 0..127
    int beg = g_start[g], end = g_start[g + 1];
    float acc = 0.0f;
    int n = beg;
    for (; n + 3 < end; n += 4) {
        float a0 = h[(size_t)n * DD + t];
        float a1 = h[(size_t)(n + 1) * DD + t];
        float a2 = h[(size_t)(n + 2) * DD + t];
        float a3 = h[(size_t)(n + 3) * DD + t];
        acc += a0 + a1 + a2 + a3;
    }
    for (; n < end; ++n) acc += h[(size_t)n * DD + t];
    float cnt = (float)(end - beg);
    out[(size_t)g * DD + t] = acc / fmaxf(cnt, 1.0f);
}

extern "C" void kernel_launch(void* const* d_in, const int* in_sizes, int n_in,
                              void* d_out, int out_size, void* d_ws, size_t ws_size,
                              hipStream_t stream) {
    const float* feats = (const float*)d_in[0];
    const float* W = (const float*)d_in[1];
    const float* b = (const float*)d_in[2];
    const int* src = (const int*)d_in[3];
    const int* dst = (const int*)d_in[4];
    const int* gid = (const int*)d_in[5];
    float* out = (float*)d_out;
    const int N = in_sizes[0] / DD;  // 50000
    const int E = in_sizes[3];       // 800000

    char* ws = (char*)d_ws;
    size_t off = 0;
    auto take = [&](size_t bytes) {
        char* p = ws + off;
        off = (off + bytes + 255) & ~(size_t)255;
        return p;
    };
    float* norm_out = (float*)take((size_t)N * 4);
    float* norm_in  = (float*)take((size_t)N * 4);
    int*   deg_in   = (int*)take((size_t)N * 4);
    int*   row_ptr  = (int*)take((size_t)(N + 1) * 4);
    int*   col_src  = (int*)take((size_t)E * 4);
    int*   g_start  = (int*)take((size_t)(GG + 1) * 4);
    int*   bsum     = (int*)take((size_t)1024 * 4);
    float* X        = (float*)take((size_t)N * DD * 4);  // scaled h
    float* Y        = (float*)take((size_t)N * DD * 4);  // agg output

    // choose NC copies to fit remaining workspace (3 arrays of NC*N ints)
    int NC = 32;
    while (NC > 1 && off + 3 * ((size_t)NC * N * 4 + 256) > ws_size) NC >>= 1;
    int* hist_out = (int*)take((size_t)NC * N * 4);
    int* hist_in  = (int*)take((size_t)NC * N * 4);
    int* fbase    = (int*)take((size_t)NC * N * 4);

    hipMemsetAsync(hist_out, 0, (size_t)NC * N * 4, stream);
    hipMemsetAsync(hist_in, 0, (size_t)NC * N * 4, stream);

    const int nblk = (N + 1023) / 1024;          // scan chunks
    const int eblk = (E + 1023) / 1024;          // edge blocks (4 edges/thread)

    k_hist<<<eblk, 256, 0, stream>>>(src, dst, hist_out, hist_in, E, N, NC);
    k_reduce<<<(N + 255) / 256, 256, 0, stream>>>(hist_out, hist_in, norm_out, norm_in, deg_in, N, NC);
    k_gstart<<<1, 512, 0, stream>>>(gid, g_start, N, GG);
    k_scan_a<<<nblk, 256, 0, stream>>>(deg_in, bsum, N);
    k_scan_b<<<1, 64, 0, stream>>>(bsum, nblk, row_ptr, N);
    k_scan_c<<<nblk, 256, 0, stream>>>(deg_in, bsum, row_ptr, N);
    k_base<<<(N + 255) / 256, 256, 0, stream>>>(hist_in, row_ptr, fbase, N, NC);
    k_fill<<<eblk, 256, 0, stream>>>(src, dst, fbase, col_src, E, N, NC);

    // layer 0 input: feats pre-scaled by norm_out
    k_scale<<<(N * 32 + 255) / 256, 256, 0, stream>>>(feats, norm_out, X, N);

    for (int l = 0; l < 3; ++l) {
        k_agg<<<(N + 7) / 8, 256, 0, stream>>>(X, norm_in, row_ptr, col_src, Y, N);
        const float* sc = (l < 2) ? norm_out : nullptr;
        k_mm<<<(N + 63) / 64, 256, 0, stream>>>(Y, W + (size_t)l * DD * DD, b + (size_t)l * DD, sc, X, N);
    }
    k_pool<<<GG, 128, 0, stream>>>(X, g_start, out);
}

// Round 5
// 372.092 us; speedup vs baseline: 1.3573x; 1.3573x over previous
//
#include <hip/hip_runtime.h>
#include <hip/hip_fp16.h>

#define DD 128
#define GG 256
#define RANGES 8
#define RSMAX 6400
#define NCHUNK 32

__device__ inline uint2 pack_half4(float4 v) {
    __half2 a = __floats2half2_rn(v.x, v.y);
    __half2 b = __floats2half2_rn(v.z, v.w);
    uint2 u;
    u.x = *reinterpret_cast<unsigned int*>(&a);
    u.y = *reinterpret_cast<unsigned int*>(&b);
    return u;
}

__device__ inline float4 unpack_half4(uint2 u) {
    __half2 a = *reinterpret_cast<__half2*>(&u.x);
    __half2 b = *reinterpret_cast<__half2*>(&u.y);
    float2 fa = __half22float2(a);
    float2 fb = __half22float2(b);
    return make_float4(fa.x, fa.y, fb.x, fb.y);
}

// ---------------- LDS range-partitioned histogram ----------------
// grid = RANGES * C blocks; block (r,c): count chunk c's edges into LDS hist
// for node range r, then dump partials pout[c][range], pin[c][range].
__global__ __launch_bounds__(256) void k_hist2(const int* __restrict__ src, const int* __restrict__ dst,
                                               int* __restrict__ pout, int* __restrict__ pin,
                                               int E, int N, int C, int RS, int L) {
    __shared__ int ho[RSMAX];
    __shared__ int hi[RSMAX];
    int r = blockIdx.x / C;
    int c = blockIdx.x % C;
    int r0 = r * RS;
    int r1 = min(r0 + RS, N);
    int nb = r1 - r0;
    for (int i = threadIdx.x; i < nb; i += 256) { ho[i] = 0; hi[i] = 0; }
    __syncthreads();
    int e0 = c * L, e1 = min(e0 + L, E);
    for (int e = e0 + threadIdx.x * 4; e < e1; e += 1024) {
        if (e + 3 < e1) {
            int4 s4 = *(const int4*)&src[e];
            int4 d4 = *(const int4*)&dst[e];
            if (s4.x >= r0 && s4.x < r1) atomicAdd(&ho[s4.x - r0], 1);
            if (s4.y >= r0 && s4.y < r1) atomicAdd(&ho[s4.y - r0], 1);
            if (s4.z >= r0 && s4.z < r1) atomicAdd(&ho[s4.z - r0], 1);
            if (s4.w >= r0 && s4.w < r1) atomicAdd(&ho[s4.w - r0], 1);
            if (d4.x >= r0 && d4.x < r1) atomicAdd(&hi[d4.x - r0], 1);
            if (d4.y >= r0 && d4.y < r1) atomicAdd(&hi[d4.y - r0], 1);
            if (d4.z >= r0 && d4.z < r1) atomicAdd(&hi[d4.z - r0], 1);
            if (d4.w >= r0 && d4.w < r1) atomicAdd(&hi[d4.w - r0], 1);
        } else {
            for (int j = 0; j < 4 && e + j < e1; ++j) {
                int s = src[e + j], d = dst[e + j];
                if (s >= r0 && s < r1) atomicAdd(&ho[s - r0], 1);
                if (d >= r0 && d < r1) atomicAdd(&hi[d - r0], 1);
            }
        }
    }
    __syncthreads();
    for (int i = threadIdx.x; i < nb; i += 256) {
        pout[(size_t)c * N + r0 + i] = ho[i];
        pin[(size_t)c * N + r0 + i] = hi[i];
    }
}

// reduce partials -> deg_in (for scan), norms
__global__ void k_reduce(const int* __restrict__ pout, const int* __restrict__ pin,
                         float* __restrict__ norm_out, float* __restrict__ norm_in,
                         int* __restrict__ deg_in, int N, int C) {
    int n = blockIdx.x * blockDim.x + threadIdx.x;
    if (n >= N) return;
    int so = 0, si = 0;
    for (int c = 0; c < C; ++c) {
        so += pout[(size_t)c * N + n];
        si += pin[(size_t)c * N + n];
    }
    norm_out[n] = rsqrtf(fmaxf((float)so, 1.0f));
    norm_in[n] = rsqrtf(fmaxf((float)si, 1.0f));
    deg_in[n] = si;
}

// per-(chunk,node) fill base: base[c][n] = row_ptr[n] + sum_{c'<c} pin[c'][n]
__global__ void k_base(const int* __restrict__ pin, const int* __restrict__ row_ptr,
                       int* __restrict__ base, int N, int C) {
    int n = blockIdx.x * blockDim.x + threadIdx.x;
    if (n >= N) return;
    int run = row_ptr[n];
    for (int c = 0; c < C; ++c) {
        int h = pin[(size_t)c * N + n];
        base[(size_t)c * N + n] = run;
        run += h;
    }
}

// g_start[g] = lower_bound(gid, g), g in [0, G]; gid sorted.
__global__ void k_gstart(const int* __restrict__ gid, int* g_start, int N, int G) {
    int g = blockIdx.x * blockDim.x + threadIdx.x;
    if (g > G) return;
    int lo = 0, hi = N;
    while (lo < hi) {
        int mid = (lo + hi) >> 1;
        if (gid[mid] < g) lo = mid + 1; else hi = mid;
    }
    g_start[g] = lo;
}

// ---------------- 3-phase scan: deg_in -> row_ptr ----------------
__global__ __launch_bounds__(256) void k_scan_a(const int* __restrict__ deg, int* bsum, int n) {
    __shared__ int wsum[4];
    int base = blockIdx.x * 1024 + threadIdx.x * 4;
    int s = 0;
    #pragma unroll
    for (int j = 0; j < 4; ++j) s += (base + j < n) ? deg[base + j] : 0;
    #pragma unroll
    for (int off = 32; off; off >>= 1) s += __shfl_xor(s, off);
    int lane = threadIdx.x & 63, w = threadIdx.x >> 6;
    if (lane == 0) wsum[w] = s;
    __syncthreads();
    if (threadIdx.x == 0) bsum[blockIdx.x] = wsum[0] + wsum[1] + wsum[2] + wsum[3];
}

__global__ void k_scan_b(int* bsum, int nblk, int* row_ptr, int n) {
    int lane = threadIdx.x;  // 64 threads
    int carry = 0;
    for (int base = 0; base < nblk; base += 64) {
        int i = base + lane;
        int v = (i < nblk) ? bsum[i] : 0;
        int s = v;
        #pragma unroll
        for (int off = 1; off < 64; off <<= 1) {
            int u = __shfl_up(s, off);
            if (lane >= off) s += u;
        }
        if (i < nblk) bsum[i] = carry + s - v;  // exclusive
        carry += __shfl(s, 63);
    }
    if (lane == 0) row_ptr[n] = carry;
}

__global__ __launch_bounds__(256) void k_scan_c(const int* __restrict__ deg, const int* __restrict__ bsum,
                                                int* row_ptr, int n) {
    __shared__ int wsum[4];
    int t = threadIdx.x;
    int base = blockIdx.x * 1024 + t * 4;
    int v[4];
    #pragma unroll
    for (int j = 0; j < 4; ++j) v[j] = (base + j < n) ? deg[base + j] : 0;
    int ts = v[0] + v[1] + v[2] + v[3];
    int lane = t & 63, w = t >> 6;
    int incl = ts;
    #pragma unroll
    for (int off = 1; off < 64; off <<= 1) {
        int u = __shfl_up(incl, off);
        if (lane >= off) incl += u;
    }
    if (lane == 63) wsum[w] = incl;
    __syncthreads();
    int woff = 0;
    for (int j = 0; j < w; ++j) woff += wsum[j];
    int run = bsum[blockIdx.x] + woff + incl - ts;
    #pragma unroll
    for (int j = 0; j < 4; ++j) {
        if (base + j < n) row_ptr[base + j] = run;
        run += v[j];
    }
}

// fill CSR via LDS slot counters; same (range,chunk) mapping as k_hist2.
__global__ __launch_bounds__(256) void k_fill2(const int* __restrict__ src, const int* __restrict__ dst,
                                               const int* __restrict__ base, int* __restrict__ col_src,
                                               int E, int N, int C, int RS, int L) {
    __shared__ int cnt[RSMAX];
    int r = blockIdx.x / C;
    int c = blockIdx.x % C;
    int r0 = r * RS;
    int r1 = min(r0 + RS, N);
    int nb = r1 - r0;
    for (int i = threadIdx.x; i < nb; i += 256) cnt[i] = 0;
    __syncthreads();
    const int* bc = base + (size_t)c * N;
    int e0 = c * L, e1 = min(e0 + L, E);
    for (int e = e0 + threadIdx.x * 4; e < e1; e += 1024) {
        if (e + 3 < e1) {
            int4 s4 = *(const int4*)&src[e];
            int4 d4 = *(const int4*)&dst[e];
            if (d4.x >= r0 && d4.x < r1) { int o = atomicAdd(&cnt[d4.x - r0], 1); col_src[bc[d4.x] + o] = s4.x; }
            if (d4.y >= r0 && d4.y < r1) { int o = atomicAdd(&cnt[d4.y - r0], 1); col_src[bc[d4.y] + o] = s4.y; }
            if (d4.z >= r0 && d4.z < r1) { int o = atomicAdd(&cnt[d4.z - r0], 1); col_src[bc[d4.z] + o] = s4.z; }
            if (d4.w >= r0 && d4.w < r1) { int o = atomicAdd(&cnt[d4.w - r0], 1); col_src[bc[d4.w] + o] = s4.w; }
        } else {
            for (int j = 0; j < 4 && e + j < e1; ++j) {
                int s = src[e + j], d = dst[e + j];
                if (d >= r0 && d < r1) { int o = atomicAdd(&cnt[d - r0], 1); col_src[bc[d] + o] = s; }
            }
        }
    }
}

// pre-scale rows to half: Xh[n] = half(feats[n] * norm_out[n])
__global__ void k_scale(const float* __restrict__ h, const float* __restrict__ norm_out,
                        uint2* __restrict__ Xh, int N) {
    int i = blockIdx.x * blockDim.x + threadIdx.x;  // over N*32 quads
    if (i < N * 32) {
        int n = i >> 5;
        float4 v = ((const float4*)h)[i];
        float s = norm_out[n];
        v.x *= s; v.y *= s; v.z *= s; v.w *= s;
        Xh[i] = pack_half4(v);
    }
}

// pull-mode aggregation from half rows (pre-scaled by norm_out), fp32 accumulate.
// 32 threads/node (uint2 = 4 halves each), 8 nodes per 256-thread block, unroll x4.
__global__ __launch_bounds__(256) void k_agg(const uint2* __restrict__ Xh, const float* __restrict__ norm_in,
                                             const int* __restrict__ row_ptr, const int* __restrict__ col_src,
                                             float* __restrict__ agg, int N) {
    int t = threadIdx.x;
    int tc = t & 31;          // half-quad index within row
    int n = blockIdx.x * 8 + (t >> 5);
    if (n >= N) return;
    int beg = row_ptr[n], end = row_ptr[n + 1];
    float4 acc = make_float4(0.f, 0.f, 0.f, 0.f);
    int k = beg;
    for (; k + 3 < end; k += 4) {
        int s0 = col_src[k];
        int s1 = col_src[k + 1];
        int s2 = col_src[k + 2];
        int s3 = col_src[k + 3];
        float4 v0 = unpack_half4(Xh[(size_t)s0 * 32 + tc]);
        float4 v1 = unpack_half4(Xh[(size_t)s1 * 32 + tc]);
        float4 v2 = unpack_half4(Xh[(size_t)s2 * 32 + tc]);
        float4 v3 = unpack_half4(Xh[(size_t)s3 * 32 + tc]);
        acc.x += v0.x + v1.x + v2.x + v3.x;
        acc.y += v0.y + v1.y + v2.y + v3.y;
        acc.z += v0.z + v1.z + v2.z + v3.z;
        acc.w += v0.w + v1.w + v2.w + v3.w;
    }
    for (; k < end; ++k) {
        int s = col_src[k];
        float4 v = unpack_half4(Xh[(size_t)s * 32 + tc]);
        acc.x += v.x; acc.y += v.y; acc.z += v.z; acc.w += v.w;
    }
    float ni = norm_in[n];
    acc.x *= ni; acc.y *= ni; acc.z *= ni; acc.w *= ni;
    *(float4*)&agg[(size_t)n * DD + tc * 4] = acc;
}

// GEMM: z = relu(A[n] @ W + b); if outh: outh[n] = half(z * scale[n]); else outf[n] = z.
__global__ __launch_bounds__(256) void k_mm(const float* __restrict__ A, const float* __restrict__ Wl,
                                            const float* __restrict__ bl, const float* __restrict__ scale,
                                            float* __restrict__ outf, uint2* __restrict__ outh, int N) {
    __shared__ float Wlds[32 * 128];  // 16 KB
    __shared__ float Alds[64 * 32];   // 8 KB
    int tid = threadIdx.x;
    int tj = tid & 31;
    int tn = tid >> 5;
    int n0 = blockIdx.x * 64;
    float acc[8][4] = {};

    for (int kk = 0; kk < 128; kk += 32) {
        __syncthreads();
        for (int q = tid; q < 1024; q += 256) {
            int r = q >> 5;
            int c = (q & 31) * 4;
            *(float4*)&Wlds[r * 128 + c] = *(const float4*)&Wl[(size_t)(kk + r) * 128 + c];
        }
        for (int q = tid; q < 512; q += 256) {
            int r = q >> 3;
            int c = (q & 7) * 4;
            int n = n0 + r;
            float4 v = make_float4(0.f, 0.f, 0.f, 0.f);
            if (n < N) v = *(const float4*)&A[(size_t)n * 128 + kk + c];
            *(float4*)&Alds[r * 32 + c] = v;
        }
        __syncthreads();
        #pragma unroll 4
        for (int kl = 0; kl < 32; ++kl) {
            float4 w = *(float4*)&Wlds[kl * 128 + tj * 4];
            #pragma unroll
            for (int i = 0; i < 8; ++i) {
                float a = Alds[(tn * 8 + i) * 32 + kl];
                acc[i][0] += a * w.x;
                acc[i][1] += a * w.y;
                acc[i][2] += a * w.z;
                acc[i][3] += a * w.w;
            }
        }
    }
    float4 bv = *(const float4*)&bl[tj * 4];
    #pragma unroll
    for (int i = 0; i < 8; ++i) {
        int n = n0 + tn * 8 + i;
        if (n < N) {
            float4 o;
            o.x = fmaxf(acc[i][0] + bv.x, 0.f);
            o.y = fmaxf(acc[i][1] + bv.y, 0.f);
            o.z = fmaxf(acc[i][2] + bv.z, 0.f);
            o.w = fmaxf(acc[i][3] + bv.w, 0.f);
            if (outh) {
                float sc = scale[n];
                o.x *= sc; o.y *= sc; o.z *= sc; o.w *= sc;
                outh[(size_t)n * 32 + tj] = pack_half4(o);
            } else {
                *(float4*)&outf[(size_t)n * 128 + tj * 4] = o;
            }
        }
    }
}

// pooled mean readout: one block per graph, contiguous row range, no atomics.
__global__ __launch_bounds__(128) void k_pool(const float* __restrict__ h, const int* __restrict__ g_start,
                                              float* __restrict__ out) {
    int g = blockIdx.x;
    int t = threadIdx.x;  // 0..127
    int beg = g_start[g], end = g_start[g + 1];
    float acc = 0.0f;
    int n = beg;
    for (; n + 3 < end; n += 4) {
        float a0 = h[(size_t)n * DD + t];
        float a1 = h[(size_t)(n + 1) * DD + t];
        float a2 = h[(size_t)(n + 2) * DD + t];
        float a3 = h[(size_t)(n + 3) * DD + t];
        acc += a0 + a1 + a2 + a3;
    }
    for (; n < end; ++n) acc += h[(size_t)n * DD + t];
    float cnt = (float)(end - beg);
    out[(size_t)g * DD + t] = acc / fmaxf(cnt, 1.0f);
}

extern "C" void kernel_launch(void* const* d_in, const int* in_sizes, int n_in,
                              void* d_out, int out_size, void* d_ws, size_t ws_size,
                              hipStream_t stream) {
    const float* feats = (const float*)d_in[0];
    const float* W = (const float*)d_in[1];
    const float* b = (const float*)d_in[2];
    const int* src = (const int*)d_in[3];
    const int* dst = (const int*)d_in[4];
    const int* gid = (const int*)d_in[5];
    float* out = (float*)d_out;
    const int N = in_sizes[0] / DD;  // 50000
    const int E = in_sizes[3];       // 800000

    const int C = NCHUNK;                       // edge chunks
    const int RS = (N + RANGES - 1) / RANGES;   // node range size (<= RSMAX)
    const int L = (((E + C - 1) / C) + 3) & ~3; // chunk length, mult of 4

    char* ws = (char*)d_ws;
    size_t off = 0;
    auto take = [&](size_t bytes) {
        char* p = ws + off;
        off = (off + bytes + 255) & ~(size_t)255;
        return p;
    };
    float* norm_out = (float*)take((size_t)N * 4);
    float* norm_in  = (float*)take((size_t)N * 4);
    int*   deg_in   = (int*)take((size_t)N * 4);
    int*   row_ptr  = (int*)take((size_t)(N + 1) * 4);
    int*   col_src  = (int*)take((size_t)E * 4);
    int*   g_start  = (int*)take((size_t)(GG + 1) * 4);
    int*   bsum     = (int*)take((size_t)1024 * 4);
    uint2* Xh       = (uint2*)take((size_t)N * DD * 2);   // half features (12.8 MB)
    float* Y        = (float*)take((size_t)N * DD * 4);   // agg output (25.6 MB)
    // union region: preprocessing partials (3*C*N*4 = 19.2 MB) then final-layer F (25.6 MB)
    size_t part_bytes = 3 * ((size_t)C * N * 4 + 256);
    size_t f_bytes = (size_t)N * DD * 4;
    char* uni = take(part_bytes > f_bytes ? part_bytes : f_bytes);
    int* pout  = (int*)uni;
    int* pin   = (int*)(uni + ((size_t)C * N * 4 + 255 & ~(size_t)255));
    int* fbase = (int*)(uni + 2 * (((size_t)C * N * 4 + 255) & ~(size_t)255));
    float* F   = (float*)uni;  // alias: used only after preprocessing completes

    const int nblk = (N + 1023) / 1024;

    k_hist2<<<RANGES * C, 256, 0, stream>>>(src, dst, pout, pin, E, N, C, RS, L);
    k_reduce<<<(N + 255) / 256, 256, 0, stream>>>(pout, pin, norm_out, norm_in, deg_in, N, C);
    k_gstart<<<1, 512, 0, stream>>>(gid, g_start, N, GG);
    k_scan_a<<<nblk, 256, 0, stream>>>(deg_in, bsum, N);
    k_scan_b<<<1, 64, 0, stream>>>(bsum, nblk, row_ptr, N);
    k_scan_c<<<nblk, 256, 0, stream>>>(deg_in, bsum, row_ptr, N);
    k_base<<<(N + 255) / 256, 256, 0, stream>>>(pin, row_ptr, fbase, N, C);
    k_fill2<<<RANGES * C, 256, 0, stream>>>(src, dst, fbase, col_src, E, N, C, RS, L);

    // layer 0 input: feats pre-scaled by norm_out, stored half
    k_scale<<<(N * 32 + 255) / 256, 256, 0, stream>>>(feats, norm_out, Xh, N);

    for (int l = 0; l < 3; ++l) {
        k_agg<<<(N + 7) / 8, 256, 0, stream>>>(Xh, norm_in, row_ptr, col_src, Y, N);
        const float* Wl = W + (size_t)l * DD * DD;
        const float* bl = b + (size_t)l * DD;
        if (l < 2)
            k_mm<<<(N + 63) / 64, 256, 0, stream>>>(Y, Wl, bl, norm_out, nullptr, Xh, N);
        else
            k_mm<<<(N + 63) / 64, 256, 0, stream>>>(Y, Wl, bl, nullptr, F, nullptr, N);
    }
    k_pool<<<GG, 128, 0, stream>>>(F, g_start, out);
}

// Round 6
// 342.384 us; speedup vs baseline: 1.4750x; 1.0868x over previous
//
#include <hip/hip_runtime.h>
#include <hip/hip_fp16.h>

#define DD 128
#define GG 256
#define RANGES 8
#define RSMAX 6400
#define NCHUNK 32

typedef _Float16 half8 __attribute__((ext_vector_type(8)));
typedef float floatx4 __attribute__((ext_vector_type(4)));

__device__ inline uint2 pack_half4(float4 v) {
    __half2 a = __floats2half2_rn(v.x, v.y);
    __half2 b = __floats2half2_rn(v.z, v.w);
    uint2 u;
    u.x = *reinterpret_cast<unsigned int*>(&a);
    u.y = *reinterpret_cast<unsigned int*>(&b);
    return u;
}

__device__ inline float4 unpack_half4(uint2 u) {
    __half2 a = *reinterpret_cast<__half2*>(&u.x);
    __half2 b = *reinterpret_cast<__half2*>(&u.y);
    float2 fa = __half22float2(a);
    float2 fb = __half22float2(b);
    return make_float4(fa.x, fa.y, fb.x, fb.y);
}

// ---------------- LDS range-partitioned histogram ----------------
__global__ __launch_bounds__(256) void k_hist2(const int* __restrict__ src, const int* __restrict__ dst,
                                               int* __restrict__ pout, int* __restrict__ pin,
                                               int E, int N, int C, int RS, int L) {
    __shared__ int ho[RSMAX];
    __shared__ int hi[RSMAX];
    int r = blockIdx.x / C;
    int c = blockIdx.x % C;
    int r0 = r * RS;
    int r1 = min(r0 + RS, N);
    int nb = r1 - r0;
    for (int i = threadIdx.x; i < nb; i += 256) { ho[i] = 0; hi[i] = 0; }
    __syncthreads();
    int e0 = c * L, e1 = min(e0 + L, E);
    for (int e = e0 + threadIdx.x * 4; e < e1; e += 1024) {
        if (e + 3 < e1) {
            int4 s4 = *(const int4*)&src[e];
            int4 d4 = *(const int4*)&dst[e];
            if (s4.x >= r0 && s4.x < r1) atomicAdd(&ho[s4.x - r0], 1);
            if (s4.y >= r0 && s4.y < r1) atomicAdd(&ho[s4.y - r0], 1);
            if (s4.z >= r0 && s4.z < r1) atomicAdd(&ho[s4.z - r0], 1);
            if (s4.w >= r0 && s4.w < r1) atomicAdd(&ho[s4.w - r0], 1);
            if (d4.x >= r0 && d4.x < r1) atomicAdd(&hi[d4.x - r0], 1);
            if (d4.y >= r0 && d4.y < r1) atomicAdd(&hi[d4.y - r0], 1);
            if (d4.z >= r0 && d4.z < r1) atomicAdd(&hi[d4.z - r0], 1);
            if (d4.w >= r0 && d4.w < r1) atomicAdd(&hi[d4.w - r0], 1);
        } else {
            for (int j = 0; j < 4 && e + j < e1; ++j) {
                int s = src[e + j], d = dst[e + j];
                if (s >= r0 && s < r1) atomicAdd(&ho[s - r0], 1);
                if (d >= r0 && d < r1) atomicAdd(&hi[d - r0], 1);
            }
        }
    }
    __syncthreads();
    for (int i = threadIdx.x; i < nb; i += 256) {
        pout[(size_t)c * N + r0 + i] = ho[i];
        pin[(size_t)c * N + r0 + i] = hi[i];
    }
}

__global__ void k_reduce(const int* __restrict__ pout, const int* __restrict__ pin,
                         float* __restrict__ norm_out, float* __restrict__ norm_in,
                         int* __restrict__ deg_in, int N, int C) {
    int n = blockIdx.x * blockDim.x + threadIdx.x;
    if (n >= N) return;
    int so = 0, si = 0;
    for (int c = 0; c < C; ++c) {
        so += pout[(size_t)c * N + n];
        si += pin[(size_t)c * N + n];
    }
    norm_out[n] = rsqrtf(fmaxf((float)so, 1.0f));
    norm_in[n] = rsqrtf(fmaxf((float)si, 1.0f));
    deg_in[n] = si;
}

__global__ void k_base(const int* __restrict__ pin, const int* __restrict__ row_ptr,
                       int* __restrict__ base, int N, int C) {
    int n = blockIdx.x * blockDim.x + threadIdx.x;
    if (n >= N) return;
    int run = row_ptr[n];
    for (int c = 0; c < C; ++c) {
        int h = pin[(size_t)c * N + n];
        base[(size_t)c * N + n] = run;
        run += h;
    }
}

__global__ void k_gstart(const int* __restrict__ gid, int* g_start, int N, int G) {
    int g = blockIdx.x * blockDim.x + threadIdx.x;
    if (g > G) return;
    int lo = 0, hi = N;
    while (lo < hi) {
        int mid = (lo + hi) >> 1;
        if (gid[mid] < g) lo = mid + 1; else hi = mid;
    }
    g_start[g] = lo;
}

// ---------------- 3-phase scan ----------------
__global__ __launch_bounds__(256) void k_scan_a(const int* __restrict__ deg, int* bsum, int n) {
    __shared__ int wsum[4];
    int base = blockIdx.x * 1024 + threadIdx.x * 4;
    int s = 0;
    #pragma unroll
    for (int j = 0; j < 4; ++j) s += (base + j < n) ? deg[base + j] : 0;
    #pragma unroll
    for (int off = 32; off; off >>= 1) s += __shfl_xor(s, off);
    int lane = threadIdx.x & 63, w = threadIdx.x >> 6;
    if (lane == 0) wsum[w] = s;
    __syncthreads();
    if (threadIdx.x == 0) bsum[blockIdx.x] = wsum[0] + wsum[1] + wsum[2] + wsum[3];
}

__global__ void k_scan_b(int* bsum, int nblk, int* row_ptr, int n) {
    int lane = threadIdx.x;
    int carry = 0;
    for (int base = 0; base < nblk; base += 64) {
        int i = base + lane;
        int v = (i < nblk) ? bsum[i] : 0;
        int s = v;
        #pragma unroll
        for (int off = 1; off < 64; off <<= 1) {
            int u = __shfl_up(s, off);
            if (lane >= off) s += u;
        }
        if (i < nblk) bsum[i] = carry + s - v;
        carry += __shfl(s, 63);
    }
    if (lane == 0) row_ptr[n] = carry;
}

__global__ __launch_bounds__(256) void k_scan_c(const int* __restrict__ deg, const int* __restrict__ bsum,
                                                int* row_ptr, int n) {
    __shared__ int wsum[4];
    int t = threadIdx.x;
    int base = blockIdx.x * 1024 + t * 4;
    int v[4];
    #pragma unroll
    for (int j = 0; j < 4; ++j) v[j] = (base + j < n) ? deg[base + j] : 0;
    int ts = v[0] + v[1] + v[2] + v[3];
    int lane = t & 63, w = t >> 6;
    int incl = ts;
    #pragma unroll
    for (int off = 1; off < 64; off <<= 1) {
        int u = __shfl_up(incl, off);
        if (lane >= off) incl += u;
    }
    if (lane == 63) wsum[w] = incl;
    __syncthreads();
    int woff = 0;
    for (int j = 0; j < w; ++j) woff += wsum[j];
    int run = bsum[blockIdx.x] + woff + incl - ts;
    #pragma unroll
    for (int j = 0; j < 4; ++j) {
        if (base + j < n) row_ptr[base + j] = run;
        run += v[j];
    }
}

// fill CSR via LDS slot counters
__global__ __launch_bounds__(256) void k_fill2(const int* __restrict__ src, const int* __restrict__ dst,
                                               const int* __restrict__ base, int* __restrict__ col_src,
                                               int E, int N, int C, int RS, int L) {
    __shared__ int cnt[RSMAX];
    int r = blockIdx.x / C;
    int c = blockIdx.x % C;
    int r0 = r * RS;
    int r1 = min(r0 + RS, N);
    int nb = r1 - r0;
    for (int i = threadIdx.x; i < nb; i += 256) cnt[i] = 0;
    __syncthreads();
    const int* bc = base + (size_t)c * N;
    int e0 = c * L, e1 = min(e0 + L, E);
    for (int e = e0 + threadIdx.x * 4; e < e1; e += 1024) {
        if (e + 3 < e1) {
            int4 s4 = *(const int4*)&src[e];
            int4 d4 = *(const int4*)&dst[e];
            if (d4.x >= r0 && d4.x < r1) { int o = atomicAdd(&cnt[d4.x - r0], 1); col_src[bc[d4.x] + o] = s4.x; }
            if (d4.y >= r0 && d4.y < r1) { int o = atomicAdd(&cnt[d4.y - r0], 1); col_src[bc[d4.y] + o] = s4.y; }
            if (d4.z >= r0 && d4.z < r1) { int o = atomicAdd(&cnt[d4.z - r0], 1); col_src[bc[d4.z] + o] = s4.z; }
            if (d4.w >= r0 && d4.w < r1) { int o = atomicAdd(&cnt[d4.w - r0], 1); col_src[bc[d4.w] + o] = s4.w; }
        } else {
            for (int j = 0; j < 4 && e + j < e1; ++j) {
                int s = src[e + j], d = dst[e + j];
                if (d >= r0 && d < r1) { int o = atomicAdd(&cnt[d - r0], 1); col_src[bc[d] + o] = s; }
            }
        }
    }
}

// W[l] f32 [k][n] -> Wt half [n][k]
__global__ void k_wconv(const float* __restrict__ W, __half* __restrict__ Wt) {
    int i = blockIdx.x * blockDim.x + threadIdx.x;  // 3*16384
    if (i >= 3 * 16384) return;
    int l = i >> 14;
    int rem = i & 16383;
    int n = rem >> 7;
    int k = rem & 127;
    Wt[(size_t)l * 16384 + n * 128 + k] = __float2half(W[(size_t)l * 16384 + k * 128 + n]);
}

// pre-scale rows to half: Xh[n] = half(feats[n] * norm_out[n])
__global__ void k_scale(const float* __restrict__ h, const float* __restrict__ norm_out,
                        uint2* __restrict__ Xh, int N) {
    int i = blockIdx.x * blockDim.x + threadIdx.x;
    if (i < N * 32) {
        int n = i >> 5;
        float4 v = ((const float4*)h)[i];
        float s = norm_out[n];
        v.x *= s; v.y *= s; v.z *= s; v.w *= s;
        Xh[i] = pack_half4(v);
    }
}

// pull-mode aggregation from half rows, fp32 accumulate, half output.
__global__ __launch_bounds__(256) void k_agg(const uint2* __restrict__ Xh, const float* __restrict__ norm_in,
                                             const int* __restrict__ row_ptr, const int* __restrict__ col_src,
                                             uint2* __restrict__ Yh, int N) {
    int t = threadIdx.x;
    int tc = t & 31;
    int n = blockIdx.x * 8 + (t >> 5);
    if (n >= N) return;
    int beg = row_ptr[n], end = row_ptr[n + 1];
    float4 acc = make_float4(0.f, 0.f, 0.f, 0.f);
    int k = beg;
    for (; k + 3 < end; k += 4) {
        int s0 = col_src[k];
        int s1 = col_src[k + 1];
        int s2 = col_src[k + 2];
        int s3 = col_src[k + 3];
        float4 v0 = unpack_half4(Xh[(size_t)s0 * 32 + tc]);
        float4 v1 = unpack_half4(Xh[(size_t)s1 * 32 + tc]);
        float4 v2 = unpack_half4(Xh[(size_t)s2 * 32 + tc]);
        float4 v3 = unpack_half4(Xh[(size_t)s3 * 32 + tc]);
        acc.x += v0.x + v1.x + v2.x + v3.x;
        acc.y += v0.y + v1.y + v2.y + v3.y;
        acc.z += v0.z + v1.z + v2.z + v3.z;
        acc.w += v0.w + v1.w + v2.w + v3.w;
    }
    for (; k < end; ++k) {
        int s = col_src[k];
        float4 v = unpack_half4(Xh[(size_t)s * 32 + tc]);
        acc.x += v.x; acc.y += v.y; acc.z += v.z; acc.w += v.w;
    }
    float ni = norm_in[n];
    acc.x *= ni; acc.y *= ni; acc.z *= ni; acc.w *= ni;
    Yh[(size_t)n * 32 + tc] = pack_half4(acc);
}

// MFMA GEMM: z = relu(Yh[n] @ W + b); layers 0,1: Xh = half(z * norm_out); layer 2: F = z (f32).
// Block: 256 thr / 4 waves / 64 nodes. v_mfma_f32_16x16x32_f16.
// A-frag: A[m=lane&15][k=quad*8+j]; B-frag from Wt[n][k] (B^T) contiguous in k; C/D: col=lane&15,row=quad*4+reg.
__global__ __launch_bounds__(256) void k_mm_mfma(const __half* __restrict__ Yh, const __half* __restrict__ Wt,
                                                 const float* __restrict__ bl, const float* __restrict__ scale,
                                                 float* __restrict__ outf, __half* __restrict__ outh, int N) {
    __shared__ _Float16 Ah[64 * 136];   // padded stride 136 halves (272 B): 2-way banks = free
    __shared__ _Float16 Bt[128 * 136];
    int tid = threadIdx.x;
    int n0 = blockIdx.x * 64;

    // stage A: 64 rows x 128 halves (16 B chunks)
    for (int q = tid; q < 1024; q += 256) {
        int r = q >> 4, c = q & 15;
        int node = n0 + r;
        float4 v = make_float4(0.f, 0.f, 0.f, 0.f);
        if (node < N) v = *(const float4*)&Yh[(size_t)node * 128 + c * 8];
        *(float4*)&Ah[r * 136 + c * 8] = v;
    }
    // stage B^T: 128 rows x 128 halves
    for (int q = tid; q < 2048; q += 256) {
        int r = q >> 4, c = q & 15;
        *(float4*)&Bt[r * 136 + c * 8] = *(const float4*)&Wt[(size_t)r * 128 + c * 8];
    }
    __syncthreads();

    int wave = tid >> 6;
    int lane = tid & 63;
    int quad = lane >> 4;
    int mrow = lane & 15;
    int m0 = wave * 16;

    half8 af[4];
    #pragma unroll
    for (int kc = 0; kc < 4; ++kc)
        af[kc] = *(const half8*)&Ah[(m0 + mrow) * 136 + kc * 32 + quad * 8];

    floatx4 acc[8];
    #pragma unroll
    for (int ct = 0; ct < 8; ++ct) acc[ct] = (floatx4){0.f, 0.f, 0.f, 0.f};

    #pragma unroll
    for (int ct = 0; ct < 8; ++ct) {
        #pragma unroll
        for (int kc = 0; kc < 4; ++kc) {
            half8 bf = *(const half8*)&Bt[(ct * 16 + mrow) * 136 + kc * 32 + quad * 8];
            acc[ct] = __builtin_amdgcn_mfma_f32_16x16x32_f16(af[kc], bf, acc[ct], 0, 0, 0);
        }
    }

    // epilogue
    float sc[4];
    #pragma unroll
    for (int r = 0; r < 4; ++r) {
        int node = n0 + m0 + quad * 4 + r;
        sc[r] = (scale && node < N) ? scale[node] : 1.0f;
    }
    #pragma unroll
    for (int ct = 0; ct < 8; ++ct) {
        int col = ct * 16 + mrow;
        float bias = bl[col];
        #pragma unroll
        for (int r = 0; r < 4; ++r) {
            int node = n0 + m0 + quad * 4 + r;
            if (node < N) {
                float val = fmaxf(acc[ct][r] + bias, 0.f);
                if (outh) outh[(size_t)node * 128 + col] = __float2half(val * sc[r]);
                else outf[(size_t)node * 128 + col] = val;
            }
        }
    }
}

// pooled mean readout
__global__ __launch_bounds__(128) void k_pool(const float* __restrict__ h, const int* __restrict__ g_start,
                                              float* __restrict__ out) {
    int g = blockIdx.x;
    int t = threadIdx.x;
    int beg = g_start[g], end = g_start[g + 1];
    float acc = 0.0f;
    int n = beg;
    for (; n + 3 < end; n += 4) {
        float a0 = h[(size_t)n * DD + t];
        float a1 = h[(size_t)(n + 1) * DD + t];
        float a2 = h[(size_t)(n + 2) * DD + t];
        float a3 = h[(size_t)(n + 3) * DD + t];
        acc += a0 + a1 + a2 + a3;
    }
    for (; n < end; ++n) acc += h[(size_t)n * DD + t];
    float cnt = (float)(end - beg);
    out[(size_t)g * DD + t] = acc / fmaxf(cnt, 1.0f);
}

extern "C" void kernel_launch(void* const* d_in, const int* in_sizes, int n_in,
                              void* d_out, int out_size, void* d_ws, size_t ws_size,
                              hipStream_t stream) {
    const float* feats = (const float*)d_in[0];
    const float* W = (const float*)d_in[1];
    const float* b = (const float*)d_in[2];
    const int* src = (const int*)d_in[3];
    const int* dst = (const int*)d_in[4];
    const int* gid = (const int*)d_in[5];
    float* out = (float*)d_out;
    const int N = in_sizes[0] / DD;  // 50000
    const int E = in_sizes[3];       // 800000

    const int C = NCHUNK;
    const int RS = (N + RANGES - 1) / RANGES;
    const int L = (((E + C - 1) / C) + 3) & ~3;

    char* ws = (char*)d_ws;
    size_t off = 0;
    auto take = [&](size_t bytes) {
        char* p = ws + off;
        off = (off + bytes + 255) & ~(size_t)255;
        return p;
    };
    float* norm_out = (float*)take((size_t)N * 4);
    float* norm_in  = (float*)take((size_t)N * 4);
    int*   deg_in   = (int*)take((size_t)N * 4);
    int*   row_ptr  = (int*)take((size_t)(N + 1) * 4);
    int*   col_src  = (int*)take((size_t)E * 4);
    int*   g_start  = (int*)take((size_t)(GG + 1) * 4);
    int*   bsum     = (int*)take((size_t)1024 * 4);
    __half* Wth     = (__half*)take((size_t)3 * 16384 * 2);
    uint2* Xh       = (uint2*)take((size_t)N * DD * 2);   // half features
    uint2* Yh       = (uint2*)take((size_t)N * DD * 2);   // half agg output
    // union region: preprocessing partials then final-layer F
    size_t part_bytes = 3 * ((size_t)C * N * 4 + 256);
    size_t f_bytes = (size_t)N * DD * 4;
    char* uni = take(part_bytes > f_bytes ? part_bytes : f_bytes);
    int* pout  = (int*)uni;
    int* pin   = (int*)(uni + (((size_t)C * N * 4 + 255) & ~(size_t)255));
    int* fbase = (int*)(uni + 2 * (((size_t)C * N * 4 + 255) & ~(size_t)255));
    float* F   = (float*)uni;  // alias: used only after preprocessing completes

    const int nblk = (N + 1023) / 1024;

    k_hist2<<<RANGES * C, 256, 0, stream>>>(src, dst, pout, pin, E, N, C, RS, L);
    k_reduce<<<(N + 255) / 256, 256, 0, stream>>>(pout, pin, norm_out, norm_in, deg_in, N, C);
    k_gstart<<<1, 512, 0, stream>>>(gid, g_start, N, GG);
    k_wconv<<<(3 * 16384 + 255) / 256, 256, 0, stream>>>(W, Wth);
    k_scan_a<<<nblk, 256, 0, stream>>>(deg_in, bsum, N);
    k_scan_b<<<1, 64, 0, stream>>>(bsum, nblk, row_ptr, N);
    k_scan_c<<<nblk, 256, 0, stream>>>(deg_in, bsum, row_ptr, N);
    k_base<<<(N + 255) / 256, 256, 0, stream>>>(pin, row_ptr, fbase, N, C);
    k_fill2<<<RANGES * C, 256, 0, stream>>>(src, dst, fbase, col_src, E, N, C, RS, L);

    k_scale<<<(N * 32 + 255) / 256, 256, 0, stream>>>(feats, norm_out, Xh, N);

    for (int l = 0; l < 3; ++l) {
        k_agg<<<(N + 7) / 8, 256, 0, stream>>>(Xh, norm_in, row_ptr, col_src, Yh, N);
        const __half* Wtl = Wth + (size_t)l * 16384;
        const float* bl = b + (size_t)l * DD;
        if (l < 2)
            k_mm_mfma<<<(N + 63) / 64, 256, 0, stream>>>((const __half*)Yh, Wtl, bl, norm_out,
                                                          nullptr, (__half*)Xh, N);
        else
            k_mm_mfma<<<(N + 63) / 64, 256, 0, stream>>>((const __half*)Yh, Wtl, bl, nullptr,
                                                          F, nullptr, N);
    }
    k_pool<<<GG, 128, 0, stream>>>(F, g_start, out);
}